// Round 13
// baseline (215.357 us; speedup 1.0000x reference)
//
#include <hip/hip_runtime.h>
#include <hip/hip_bf16.h>
#include <stdint.h>

// Problem constants
constexpr int BB = 4, TT = 2048, CC = 1024, HH = 16, DD = 64;

typedef __bf16 bf16_t;
typedef bf16_t bf16x8 __attribute__((ext_vector_type(8)));
typedef bf16_t bf16x4 __attribute__((ext_vector_type(4)));
typedef float f32x4 __attribute__((ext_vector_type(4)));

// Native cast: compiler emits v_cvt_pk_bf16_f32 for adjacent pairs (RNE).
__device__ __forceinline__ unsigned short f2bf(float f) {
    union { __bf16 h; unsigned short u; } v;
    v.h = (__bf16)f;
    return v.u;
}

__device__ __forceinline__ f32x4 mfma16(bf16x8 a, bf16x8 b, f32x4 c) {
    return __builtin_amdgcn_mfma_f32_16x16x32_bf16(a, b, c, 0, 0, 0);
}

#define LOAD_LDS16(g, l)                                                      \
    __builtin_amdgcn_global_load_lds(                                         \
        (const __attribute__((address_space(1))) void*)(g),                   \
        (__attribute__((address_space(3))) void*)(l), 16, 0, 0)

// ---------------- fused f32 -> bf16 convert for all 3 arrays ----------------
__global__ __launch_bounds__(256) void cvt_all(
    const float* __restrict__ a, long na,    // quads
    const float* __restrict__ b, long nb,    // quads
    const float* __restrict__ c, long nc,    // quads
    unsigned short* __restrict__ oa, unsigned short* __restrict__ ob,
    unsigned short* __restrict__ oc) {
    const long ntot = na + nb + nc;
    long i = (long)blockIdx.x * blockDim.x + threadIdx.x;
    const long stride = (long)gridDim.x * blockDim.x;
    for (; i < ntot; i += stride) {
        const float* src;
        unsigned short* dst;
        long q = i;
        if (q < na) { src = a; dst = oa; }
        else if (q < na + nb) { q -= na; src = b; dst = ob; }
        else { q -= na + nb; src = c; dst = oc; }
        float4 v = *(const float4*)(src + q * 4);
        ushort4 o;
        o.x = f2bf(v.x); o.y = f2bf(v.y); o.z = f2bf(v.z); o.w = f2bf(v.w);
        *(ushort4*)(dst + q * 4) = o;
    }
}

// ---------------- GEMM: C[m,n] = sum_k A[m,k]*Bw[n,k] + bias[n] ----------------
// m97 structure: 128x128 tile, BK=32, 4 waves, global_load_lds(16B), dbuf LDS.
// __launch_bounds__(256,3): pin 3 blocks/CU (R10-verified: -4 us vs (256,2)).
// R8/R11 deep-pipeline rewrites both lost at K=1024 -- do not restructure.
template <int MODE>
__global__ __launch_bounds__(256, 3) void gemm_bt(
    const unsigned short* __restrict__ A,    // [M][K] bf16
    const unsigned short* __restrict__ Bw,   // [N][K] bf16
    const float* __restrict__ bias,          // [N]
    unsigned short* __restrict__ qb, unsigned short* __restrict__ kb,
    unsigned short* __restrict__ vtb, float* __restrict__ outf,
    int M, int N, int K) {
    __shared__ unsigned short As[2][128 * 32];
    __shared__ unsigned short Bs[2][128 * 32];
    const int tid = threadIdx.x;
    const int w = tid >> 6, lane = tid & 63;
    const int g = lane >> 4, q16 = lane & 15;
    const int wr = w >> 1, wc = w & 1;
    const int mbase = blockIdx.x * 128;
    const int nbase = blockIdx.y * 128;
    const int srow = lane >> 2;
    const int scol = (lane & 3) * 8;

    f32x4 acc[4][4];
#pragma unroll
    for (int i = 0; i < 4; ++i)
#pragma unroll
        for (int j = 0; j < 4; ++j) acc[i][j] = (f32x4){0.f, 0.f, 0.f, 0.f};

    const int nk = K >> 5;

    auto stage = [&](int buf, int t) {
        const int k0 = t << 5;
#pragma unroll
        for (int ii = 0; ii < 2; ++ii) {
            const int i = w + ii * 4;
            const unsigned short* ga =
                A + (long)(mbase + i * 16 + srow) * K + k0 + scol;
            LOAD_LDS16(ga, &As[buf][i * 512]);
            const unsigned short* gb =
                Bw + (long)(nbase + i * 16 + srow) * K + k0 + scol;
            LOAD_LDS16(gb, &Bs[buf][i * 512]);
        }
    };

    stage(0, 0);
    __syncthreads();
    int cur = 0;
    for (int t = 0; t < nk; ++t) {
        if (t + 1 < nk) stage(cur ^ 1, t + 1);
        bf16x8 af[4], bfr[4];
#pragma unroll
        for (int mi = 0; mi < 4; ++mi)
            af[mi] = *(const bf16x8*)&As[cur][(wr * 64 + mi * 16 + q16) * 32 + 8 * g];
#pragma unroll
        for (int ni = 0; ni < 4; ++ni)
            bfr[ni] = *(const bf16x8*)&Bs[cur][(wc * 64 + ni * 16 + q16) * 32 + 8 * g];
#pragma unroll
        for (int mi = 0; mi < 4; ++mi)
#pragma unroll
            for (int ni = 0; ni < 4; ++ni)
                acc[mi][ni] = mfma16(af[mi], bfr[ni], acc[mi][ni]);
        __syncthreads();
        cur ^= 1;
    }

#pragma unroll
    for (int mi = 0; mi < 4; ++mi) {
#pragma unroll
        for (int ni = 0; ni < 4; ++ni) {
            const int n = nbase + wc * 64 + ni * 16 + q16;
            const float bv = bias[n];
#pragma unroll
            for (int r = 0; r < 4; ++r) {
                const int m = mbase + wr * 64 + mi * 16 + 4 * g + r;
                const float val = acc[mi][ni][r] + bv;
                if (MODE == 0) {
                    const int which = n >> 10, rem = n & 1023;
                    const int h = rem >> 6, d = rem & 63;
                    const int b = m >> 11, t = m & 2047;
                    const long bh = (long)(b * HH + h);
                    if (which == 0)
                        qb[(bh * TT + t) * DD + d] = f2bf(val * 0.125f);
                    else if (which == 1)
                        kb[(bh * TT + t) * DD + d] = f2bf(val);
                    else
                        vtb[(bh * DD + d) * TT + t] = f2bf(val);
                } else {
                    outf[(long)m * N + n] = val;
                }
            }
        }
    }
}

// ------ causal flash attention (R12 + zero-shuffle PV, 5 blocks/CU) ---------
// grid: flat 2048 blocks, XCD-swizzled; LPT (bx = 31-(swz&31), longest first).
// Zero-shuffle PV: MFMA K-positions are order-invariant if A and B agree on
// the permutation. A-fragment uses the lane's OWN P values (k = 16s+4g+r):
// pa0 = {p[0][0..3], p[1][0..3]}, pa1 = {p[2][..], p[3][..]} -- P never
// touches LDS (plds deleted). B side supplies V in the same order: per ni,
// four 8B reads at chunk addrs v0, v0^16, v0^32, v0^48 (v0 accounts for the
// 16B-slot staging swizzle). Bank floor: 4 dwords/bank per b64 -- conflict-
// free. LDS = 32768 B exactly -> 5 blocks/CU (+25% waves).
__global__ __launch_bounds__(256, 5) void attn_fwd(
    const unsigned short* __restrict__ qb, const unsigned short* __restrict__ kb,
    const unsigned short* __restrict__ vtb, unsigned short* __restrict__ attb) {
    __shared__ __align__(16) unsigned short Ks[2][64 * 64];
    __shared__ __align__(16) unsigned short Vs[2][64 * 64];
    const int tid = threadIdx.x;
    const int w = tid >> 6, lane = tid & 63;
    const int g = lane >> 4, q16 = lane & 15;
    const int bid = blockIdx.x;
    const int swz = (bid & 7) * 256 + (bid >> 3);   // 2048 % 8 == 0: bijective
    const int bx = 31 - (swz & 31);                 // LPT: big bx first
    const int bh = swz >> 5;
    const int b = bh >> 4, h = bh & 15;
    const int qbase = bx * 64 + w * 16;

    const unsigned short* Q = qb + (long)bh * TT * DD;
    const unsigned short* Kp = kb + (long)bh * TT * DD;
    const unsigned short* Vt = vtb + (long)bh * DD * TT;

    const int srow = tid >> 3;                       // 0..31
    const int ssl = ((tid & 7) ^ (srow & 7)) * 8;    // swizzled col (shorts)
    unsigned short* kdst0 = &Ks[0][0] + w * 512;     // wave-uniform dests
    unsigned short* vdst0 = &Vs[0][0] + w * 512;

    auto stageKV = [&](int buf, int kt) {
        const long kb0 = (long)kt * 64;
        const unsigned short* gk = Kp + (kb0 + srow) * DD + ssl;
        const unsigned short* gv = Vt + (long)srow * TT + kb0 + ssl;
        unsigned short* kd = kdst0 + buf * 4096;
        unsigned short* vd = vdst0 + buf * 4096;
        LOAD_LDS16(gk, kd);
        LOAD_LDS16(gk + 32l * DD, kd + 2048);
        LOAD_LDS16(gv, vd);
        LOAD_LDS16(gv + 32l * TT, vd + 2048);
    };

    bf16x8 aq0 = *(const bf16x8*)&Q[(qbase + q16) * DD + 8 * g];
    bf16x8 aq1 = *(const bf16x8*)&Q[(qbase + q16) * DD + 32 + 8 * g];

    f32x4 acc[4];
#pragma unroll
    for (int i = 0; i < 4; ++i) acc[i] = (f32x4){0.f, 0.f, 0.f, 0.f};
    float mrow = -1e30f, lrow = 0.f;

    const int slot0 = (g ^ (q16 & 7)) << 3;                 // K-read slot
    const int v0 = ((g >> 1) ^ (q16 & 7)) * 8 + (g & 1) * 4; // V 8B-chunk addr
    const int nkt = bx + 1;
    stageKV(0, 0);
    __syncthreads();
    int cur = 0;
    for (int kt = 0; kt < nkt; ++kt) {
        if (kt + 1 < nkt) stageKV(cur ^ 1, kt + 1);
        const int kbase = kt * 64;
        f32x4 p[4];
#pragma unroll
        for (int s = 0; s < 4; ++s) p[s] = (f32x4){0.f, 0.f, 0.f, 0.f};
        __builtin_amdgcn_s_setprio(1);
#pragma unroll
        for (int s = 0; s < 4; ++s) {
            const int kr = (16 * s + q16) * 64;
            bf16x8 bk0 = *(const bf16x8*)&Ks[cur][kr + slot0];
            bf16x8 bk1 = *(const bf16x8*)&Ks[cur][kr + (slot0 ^ 32)];
            p[s] = mfma16(bk0, aq0, p[s]);
            p[s] = mfma16(bk1, aq1, p[s]);
        }
        __builtin_amdgcn_s_setprio(0);
        const int q = qbase + q16;
        if (kt == nkt - 1) {
#pragma unroll
            for (int s = 0; s < 4; ++s)
#pragma unroll
                for (int r = 0; r < 4; ++r)
                    if (kbase + 16 * s + 4 * g + r > q) p[s][r] = -1e30f;
        }
        float t = fmaxf(fmaxf(p[0][0], p[0][1]), fmaxf(p[0][2], p[0][3]));
#pragma unroll
        for (int s = 1; s < 4; ++s)
            t = fmaxf(t, fmaxf(fmaxf(p[s][0], p[s][1]), fmaxf(p[s][2], p[s][3])));
        t = fmaxf(t, __shfl_xor(t, 16));
        t = fmaxf(t, __shfl_xor(t, 32));
        if (__all(t - mrow <= 8.0f)) {
            float ssum = 0.f;
#pragma unroll
            for (int s = 0; s < 4; ++s)
#pragma unroll
                for (int r = 0; r < 4; ++r) {
                    p[s][r] = __expf(p[s][r] - mrow);
                    ssum += p[s][r];
                }
            ssum += __shfl_xor(ssum, 16);
            ssum += __shfl_xor(ssum, 32);
            lrow += ssum;
        } else {
            const float nm = fmaxf(mrow, t);
            const float fs = __expf(mrow - nm);
            mrow = nm;
            float ssum = 0.f;
#pragma unroll
            for (int s = 0; s < 4; ++s)
#pragma unroll
                for (int r = 0; r < 4; ++r) {
                    p[s][r] = __expf(p[s][r] - nm);
                    ssum += p[s][r];
                }
            ssum += __shfl_xor(ssum, 16);
            ssum += __shfl_xor(ssum, 32);
            lrow = lrow * fs + ssum;
            float fr[4];
#pragma unroll
            for (int r = 0; r < 4; ++r) fr[r] = __shfl(fs, 4 * g + r);
#pragma unroll
            for (int ni = 0; ni < 4; ++ni)
#pragma unroll
                for (int r = 0; r < 4; ++r) acc[ni][r] *= fr[r];
        }
        // zero-shuffle PV: pack P into A-fragments in-register
        bf16x8 pa0, pa1;
#pragma unroll
        for (int r = 0; r < 4; ++r) {
            pa0[r] = (__bf16)p[0][r];
            pa0[4 + r] = (__bf16)p[1][r];
            pa1[r] = (__bf16)p[2][r];
            pa1[4 + r] = (__bf16)p[3][r];
        }
        __builtin_amdgcn_s_setprio(1);
#pragma unroll
        for (int ni = 0; ni < 4; ++ni) {
            const unsigned short* vrow = &Vs[cur][(ni * 16 + q16) * 64];
            bf16x4 c0 = *(const bf16x4*)&vrow[v0];
            bf16x4 c1 = *(const bf16x4*)&vrow[v0 ^ 16];
            bf16x4 c2 = *(const bf16x4*)&vrow[v0 ^ 32];
            bf16x4 c3 = *(const bf16x4*)&vrow[v0 ^ 48];
            bf16x8 bv0 = __builtin_shufflevector(c0, c1, 0, 1, 2, 3, 4, 5, 6, 7);
            bf16x8 bv1 = __builtin_shufflevector(c2, c3, 0, 1, 2, 3, 4, 5, 6, 7);
            acc[ni] = mfma16(pa0, bv0, acc[ni]);
            acc[ni] = mfma16(pa1, bv1, acc[ni]);
        }
        __builtin_amdgcn_s_setprio(0);
        __syncthreads();
        cur ^= 1;
    }
    float inv[4];
#pragma unroll
    for (int r = 0; r < 4; ++r) inv[r] = 1.0f / __shfl(lrow, 4 * g + r);
#pragma unroll
    for (int ni = 0; ni < 4; ++ni)
#pragma unroll
        for (int r = 0; r < 4; ++r) {
            const int q = qbase + 4 * g + r;
            const int d = ni * 16 + q16;
            attb[(((long)b * TT + q) * HH + h) * DD + d] =
                f2bf(acc[ni][r] * inv[r]);
        }
}

extern "C" void kernel_launch(void* const* d_in, const int* in_sizes, int n_in,
                              void* d_out, int out_size, void* d_ws, size_t ws_size,
                              hipStream_t stream) {
    const float* x = (const float*)d_in[0];
    const float* Wqkv = (const float*)d_in[1];
    const float* bqkv = (const float*)d_in[2];
    const float* Wproj = (const float*)d_in[3];
    const float* bproj = (const float*)d_in[4];
    float* out = (float*)d_out;

    char* ws = (char*)d_ws;
    unsigned short* xb = (unsigned short*)(ws);                  // 16 MB (reused as attb)
    unsigned short* wqkvb = (unsigned short*)(ws + (16l << 20)); // 6 MB
    unsigned short* wprojb = (unsigned short*)(ws + (22l << 20));// 2 MB
    unsigned short* qb = (unsigned short*)(ws + (24l << 20));    // 16 MB
    unsigned short* kb = (unsigned short*)(ws + (40l << 20));    // 16 MB
    unsigned short* vtb = (unsigned short*)(ws + (56l << 20));   // 16 MB
    unsigned short* attb = xb;  // x dead after QKV GEMM; reuse

    cvt_all<<<2048, 256, 0, stream>>>(
        x, (long)BB * TT * CC / 4, Wqkv, (long)3 * CC * CC / 4, Wproj,
        (long)CC * CC / 4, xb, wqkvb, wprojb);

    gemm_bt<0><<<dim3(64, 24), 256, 0, stream>>>(xb, wqkvb, bqkv, qb, kb, vtb,
                                                 nullptr, BB * TT, 3 * CC, CC);
    attn_fwd<<<2048, 256, 0, stream>>>(qb, kb, vtb, attb);
    gemm_bt<1><<<dim3(64, 8), 256, 0, stream>>>(attb, wprojb, bproj, nullptr,
                                                nullptr, nullptr, out, BB * TT,
                                                CC, CC);
}

// Round 14
// 206.971 us; speedup vs baseline: 1.0405x; 1.0405x over previous
//
#include <hip/hip_runtime.h>
#include <hip/hip_bf16.h>
#include <stdint.h>

// Problem constants
constexpr int BB = 4, TT = 2048, CC = 1024, HH = 16, DD = 64;

typedef __bf16 bf16_t;
typedef bf16_t bf16x8 __attribute__((ext_vector_type(8)));
typedef float f32x4 __attribute__((ext_vector_type(4)));

// Native cast: compiler emits v_cvt_pk_bf16_f32 for adjacent pairs (RNE).
__device__ __forceinline__ unsigned short f2bf(float f) {
    union { __bf16 h; unsigned short u; } v;
    v.h = (__bf16)f;
    return v.u;
}

__device__ __forceinline__ f32x4 mfma16(bf16x8 a, bf16x8 b, f32x4 c) {
    return __builtin_amdgcn_mfma_f32_16x16x32_bf16(a, b, c, 0, 0, 0);
}

#define LOAD_LDS16(g, l)                                                      \
    __builtin_amdgcn_global_load_lds(                                         \
        (const __attribute__((address_space(1))) void*)(g),                   \
        (__attribute__((address_space(3))) void*)(l), 16, 0, 0)

// ---------------- fused f32 -> bf16 convert for all 3 arrays ----------------
__global__ __launch_bounds__(256) void cvt_all(
    const float* __restrict__ a, long na,    // quads
    const float* __restrict__ b, long nb,    // quads
    const float* __restrict__ c, long nc,    // quads
    unsigned short* __restrict__ oa, unsigned short* __restrict__ ob,
    unsigned short* __restrict__ oc) {
    const long ntot = na + nb + nc;
    long i = (long)blockIdx.x * blockDim.x + threadIdx.x;
    const long stride = (long)gridDim.x * blockDim.x;
    for (; i < ntot; i += stride) {
        const float* src;
        unsigned short* dst;
        long q = i;
        if (q < na) { src = a; dst = oa; }
        else if (q < na + nb) { q -= na; src = b; dst = ob; }
        else { q -= na + nb; src = c; dst = oc; }
        float4 v = *(const float4*)(src + q * 4);
        ushort4 o;
        o.x = f2bf(v.x); o.y = f2bf(v.y); o.z = f2bf(v.z); o.w = f2bf(v.w);
        *(ushort4*)(dst + q * 4) = o;
    }
}

// ---------------- GEMM: C[m,n] = sum_k A[m,k]*Bw[n,k] + bias[n] ----------------
// m97 structure: 128x128 tile, BK=32, 4 waves, global_load_lds(16B), dbuf LDS.
// __launch_bounds__(256,3): pin 3 blocks/CU (R10-verified: -4 us vs (256,2)).
// R8/R11 deep-pipeline rewrites both lost at K=1024 -- do not restructure.
// MODE 0 epilogue: q scaled by 0.125*log2e -> attn softmax runs in log2
// domain (bare v_exp_f32, no per-element *log2e mul).
template <int MODE>
__global__ __launch_bounds__(256, 3) void gemm_bt(
    const unsigned short* __restrict__ A,    // [M][K] bf16
    const unsigned short* __restrict__ Bw,   // [N][K] bf16
    const float* __restrict__ bias,          // [N]
    unsigned short* __restrict__ qb, unsigned short* __restrict__ kb,
    unsigned short* __restrict__ vtb, float* __restrict__ outf,
    int M, int N, int K) {
    __shared__ unsigned short As[2][128 * 32];
    __shared__ unsigned short Bs[2][128 * 32];
    const int tid = threadIdx.x;
    const int w = tid >> 6, lane = tid & 63;
    const int g = lane >> 4, q16 = lane & 15;
    const int wr = w >> 1, wc = w & 1;
    const int mbase = blockIdx.x * 128;
    const int nbase = blockIdx.y * 128;
    const int srow = lane >> 2;
    const int scol = (lane & 3) * 8;

    f32x4 acc[4][4];
#pragma unroll
    for (int i = 0; i < 4; ++i)
#pragma unroll
        for (int j = 0; j < 4; ++j) acc[i][j] = (f32x4){0.f, 0.f, 0.f, 0.f};

    const int nk = K >> 5;

    auto stage = [&](int buf, int t) {
        const int k0 = t << 5;
#pragma unroll
        for (int ii = 0; ii < 2; ++ii) {
            const int i = w + ii * 4;
            const unsigned short* ga =
                A + (long)(mbase + i * 16 + srow) * K + k0 + scol;
            LOAD_LDS16(ga, &As[buf][i * 512]);
            const unsigned short* gb =
                Bw + (long)(nbase + i * 16 + srow) * K + k0 + scol;
            LOAD_LDS16(gb, &Bs[buf][i * 512]);
        }
    };

    stage(0, 0);
    __syncthreads();
    int cur = 0;
    for (int t = 0; t < nk; ++t) {
        if (t + 1 < nk) stage(cur ^ 1, t + 1);
        bf16x8 af[4], bfr[4];
#pragma unroll
        for (int mi = 0; mi < 4; ++mi)
            af[mi] = *(const bf16x8*)&As[cur][(wr * 64 + mi * 16 + q16) * 32 + 8 * g];
#pragma unroll
        for (int ni = 0; ni < 4; ++ni)
            bfr[ni] = *(const bf16x8*)&Bs[cur][(wc * 64 + ni * 16 + q16) * 32 + 8 * g];
#pragma unroll
        for (int mi = 0; mi < 4; ++mi)
#pragma unroll
            for (int ni = 0; ni < 4; ++ni)
                acc[mi][ni] = mfma16(af[mi], bfr[ni], acc[mi][ni]);
        __syncthreads();
        cur ^= 1;
    }

#pragma unroll
    for (int mi = 0; mi < 4; ++mi) {
#pragma unroll
        for (int ni = 0; ni < 4; ++ni) {
            const int n = nbase + wc * 64 + ni * 16 + q16;
            const float bv = bias[n];
#pragma unroll
            for (int r = 0; r < 4; ++r) {
                const int m = mbase + wr * 64 + mi * 16 + 4 * g + r;
                const float val = acc[mi][ni][r] + bv;
                if (MODE == 0) {
                    const int which = n >> 10, rem = n & 1023;
                    const int h = rem >> 6, d = rem & 63;
                    const int b = m >> 11, t = m & 2047;
                    const long bh = (long)(b * HH + h);
                    if (which == 0)  // 0.125 * log2(e): log2-domain softmax
                        qb[(bh * TT + t) * DD + d] =
                            f2bf(val * 0.18033688011112042f);
                    else if (which == 1)
                        kb[(bh * TT + t) * DD + d] = f2bf(val);
                    else
                        vtb[(bh * DD + d) * TT + t] = f2bf(val);
                } else {
                    outf[(long)m * N + n] = val;
                }
            }
        }
    }
}

// ---------------- causal flash attention (R12 + log2-domain softmax) --------
// grid: flat 2048 blocks, XCD-swizzled; LPT (bx = 31-(swz&31), longest first).
// R12-exact structure: swapped QK^T, source-XOR-swizzled global_load_lds
// staging (dbuf), plds stride-64 XOR, defer-max, setprio on MFMA clusters,
// LDS 40960 B = 4 blocks/CU. Softmax in log2 domain (Q pre-scaled by log2e):
// exp = bare v_exp_f32 via __builtin_amdgcn_exp2f; THR = 8*log2e (same e^8
// bound on P). R13's zero-shuffle PV reverted (4x bank conflicts on 8B reads).
__global__ __launch_bounds__(256, 4) void attn_fwd(
    const unsigned short* __restrict__ qb, const unsigned short* __restrict__ kb,
    const unsigned short* __restrict__ vtb, unsigned short* __restrict__ attb) {
    __shared__ __align__(16) unsigned short Ks[2][64 * 64];
    __shared__ __align__(16) unsigned short Vs[2][64 * 64];
    __shared__ __align__(16) unsigned short plds[4][16 * 64];
    const int tid = threadIdx.x;
    const int w = tid >> 6, lane = tid & 63;
    const int g = lane >> 4, q16 = lane & 15;
    const int bid = blockIdx.x;
    const int swz = (bid & 7) * 256 + (bid >> 3);   // 2048 % 8 == 0: bijective
    const int bx = 31 - (swz & 31);                 // LPT: big bx first
    const int bh = swz >> 5;
    const int b = bh >> 4, h = bh & 15;
    const int qbase = bx * 64 + w * 16;

    const unsigned short* Q = qb + (long)bh * TT * DD;
    const unsigned short* Kp = kb + (long)bh * TT * DD;
    const unsigned short* Vt = vtb + (long)bh * DD * TT;

    const int srow = tid >> 3;                       // 0..31
    const int ssl = ((tid & 7) ^ (srow & 7)) * 8;    // swizzled col (shorts)
    unsigned short* kdst0 = &Ks[0][0] + w * 512;     // wave-uniform dests
    unsigned short* vdst0 = &Vs[0][0] + w * 512;

    auto stageKV = [&](int buf, int kt) {
        const long kb0 = (long)kt * 64;
        const unsigned short* gk = Kp + (kb0 + srow) * DD + ssl;
        const unsigned short* gv = Vt + (long)srow * TT + kb0 + ssl;
        unsigned short* kd = kdst0 + buf * 4096;
        unsigned short* vd = vdst0 + buf * 4096;
        LOAD_LDS16(gk, kd);
        LOAD_LDS16(gk + 32l * DD, kd + 2048);
        LOAD_LDS16(gv, vd);
        LOAD_LDS16(gv + 32l * TT, vd + 2048);
    };

    bf16x8 aq0 = *(const bf16x8*)&Q[(qbase + q16) * DD + 8 * g];
    bf16x8 aq1 = *(const bf16x8*)&Q[(qbase + q16) * DD + 32 + 8 * g];

    f32x4 acc[4];
#pragma unroll
    for (int i = 0; i < 4; ++i) acc[i] = (f32x4){0.f, 0.f, 0.f, 0.f};
    float mrow = -1e30f, lrow = 0.f;

    const int slot0 = (g ^ (q16 & 7)) << 3;
    const int nkt = bx + 1;
    stageKV(0, 0);
    __syncthreads();
    int cur = 0;
    for (int kt = 0; kt < nkt; ++kt) {
        if (kt + 1 < nkt) stageKV(cur ^ 1, kt + 1);
        const int kbase = kt * 64;
        f32x4 p[4];
#pragma unroll
        for (int s = 0; s < 4; ++s) p[s] = (f32x4){0.f, 0.f, 0.f, 0.f};
        __builtin_amdgcn_s_setprio(1);
#pragma unroll
        for (int s = 0; s < 4; ++s) {
            const int kr = (16 * s + q16) * 64;
            bf16x8 bk0 = *(const bf16x8*)&Ks[cur][kr + slot0];
            bf16x8 bk1 = *(const bf16x8*)&Ks[cur][kr + (slot0 ^ 32)];
            p[s] = mfma16(bk0, aq0, p[s]);
            p[s] = mfma16(bk1, aq1, p[s]);
        }
        __builtin_amdgcn_s_setprio(0);
        const int q = qbase + q16;
        if (kt == nkt - 1) {
#pragma unroll
            for (int s = 0; s < 4; ++s)
#pragma unroll
                for (int r = 0; r < 4; ++r)
                    if (kbase + 16 * s + 4 * g + r > q) p[s][r] = -1e30f;
        }
        float t = fmaxf(fmaxf(p[0][0], p[0][1]), fmaxf(p[0][2], p[0][3]));
#pragma unroll
        for (int s = 1; s < 4; ++s)
            t = fmaxf(t, fmaxf(fmaxf(p[s][0], p[s][1]), fmaxf(p[s][2], p[s][3])));
        t = fmaxf(t, __shfl_xor(t, 16));
        t = fmaxf(t, __shfl_xor(t, 32));
        if (__all(t - mrow <= 11.541560327111708f)) {  // 8*log2e
            float ssum = 0.f;
#pragma unroll
            for (int s = 0; s < 4; ++s)
#pragma unroll
                for (int r = 0; r < 4; ++r) {
                    p[s][r] = __builtin_amdgcn_exp2f(p[s][r] - mrow);
                    ssum += p[s][r];
                }
            ssum += __shfl_xor(ssum, 16);
            ssum += __shfl_xor(ssum, 32);
            lrow += ssum;
        } else {
            const float nm = fmaxf(mrow, t);
            const float fs = __builtin_amdgcn_exp2f(mrow - nm);
            mrow = nm;
            float ssum = 0.f;
#pragma unroll
            for (int s = 0; s < 4; ++s)
#pragma unroll
                for (int r = 0; r < 4; ++r) {
                    p[s][r] = __builtin_amdgcn_exp2f(p[s][r] - nm);
                    ssum += p[s][r];
                }
            ssum += __shfl_xor(ssum, 16);
            ssum += __shfl_xor(ssum, 32);
            lrow = lrow * fs + ssum;
            float fr[4];
#pragma unroll
            for (int r = 0; r < 4; ++r) fr[r] = __shfl(fs, 4 * g + r);
#pragma unroll
            for (int ni = 0; ni < 4; ++ni)
#pragma unroll
                for (int r = 0; r < 4; ++r) acc[ni][r] *= fr[r];
        }
#pragma unroll
        for (int s = 0; s < 4; ++s) {
            ushort4 pk;
            pk.x = f2bf(p[s][0]); pk.y = f2bf(p[s][1]);
            pk.z = f2bf(p[s][2]); pk.w = f2bf(p[s][3]);
            const int Gp = ((2 * s + (g >> 1)) ^ (q16 & 7)) * 8 + (g & 1) * 4;
            *(ushort4*)&plds[w][q16 * 64 + Gp] = pk;
        }
        bf16x8 pa0 = *(const bf16x8*)&plds[w][q16 * 64 + slot0];
        bf16x8 pa1 = *(const bf16x8*)&plds[w][q16 * 64 + (slot0 ^ 32)];
        __builtin_amdgcn_s_setprio(1);
#pragma unroll
        for (int ni = 0; ni < 4; ++ni) {
            const int vr = (ni * 16 + q16) * 64;
            bf16x8 bv0 = *(const bf16x8*)&Vs[cur][vr + slot0];
            bf16x8 bv1 = *(const bf16x8*)&Vs[cur][vr + (slot0 ^ 32)];
            acc[ni] = mfma16(pa0, bv0, acc[ni]);
            acc[ni] = mfma16(pa1, bv1, acc[ni]);
        }
        __builtin_amdgcn_s_setprio(0);
        __syncthreads();
        cur ^= 1;
    }
    float inv[4];
#pragma unroll
    for (int r = 0; r < 4; ++r) inv[r] = 1.0f / __shfl(lrow, 4 * g + r);
#pragma unroll
    for (int ni = 0; ni < 4; ++ni)
#pragma unroll
        for (int r = 0; r < 4; ++r) {
            const int q = qbase + 4 * g + r;
            const int d = ni * 16 + q16;
            attb[(((long)b * TT + q) * HH + h) * DD + d] =
                f2bf(acc[ni][r] * inv[r]);
        }
}

extern "C" void kernel_launch(void* const* d_in, const int* in_sizes, int n_in,
                              void* d_out, int out_size, void* d_ws, size_t ws_size,
                              hipStream_t stream) {
    const float* x = (const float*)d_in[0];
    const float* Wqkv = (const float*)d_in[1];
    const float* bqkv = (const float*)d_in[2];
    const float* Wproj = (const float*)d_in[3];
    const float* bproj = (const float*)d_in[4];
    float* out = (float*)d_out;

    char* ws = (char*)d_ws;
    unsigned short* xb = (unsigned short*)(ws);                  // 16 MB (reused as attb)
    unsigned short* wqkvb = (unsigned short*)(ws + (16l << 20)); // 6 MB
    unsigned short* wprojb = (unsigned short*)(ws + (22l << 20));// 2 MB
    unsigned short* qb = (unsigned short*)(ws + (24l << 20));    // 16 MB
    unsigned short* kb = (unsigned short*)(ws + (40l << 20));    // 16 MB
    unsigned short* vtb = (unsigned short*)(ws + (56l << 20));   // 16 MB
    unsigned short* attb = xb;  // x dead after QKV GEMM; reuse

    cvt_all<<<2048, 256, 0, stream>>>(
        x, (long)BB * TT * CC / 4, Wqkv, (long)3 * CC * CC / 4, Wproj,
        (long)CC * CC / 4, xb, wqkvb, wprojb);

    gemm_bt<0><<<dim3(64, 24), 256, 0, stream>>>(xb, wqkvb, bqkv, qb, kb, vtb,
                                                 nullptr, BB * TT, 3 * CC, CC);
    attn_fwd<<<2048, 256, 0, stream>>>(qb, kb, vtb, attb);
    gemm_bt<1><<<dim3(64, 8), 256, 0, stream>>>(attb, wprojb, bproj, nullptr,
                                                nullptr, nullptr, out, BB * TT,
                                                CC, CC);
}

// Round 15
// 200.929 us; speedup vs baseline: 1.0718x; 1.0301x over previous
//
#include <hip/hip_runtime.h>
#include <hip/hip_bf16.h>
#include <stdint.h>

// Problem constants
constexpr int BB = 4, TT = 2048, CC = 1024, HH = 16, DD = 64;

typedef __bf16 bf16_t;
typedef bf16_t bf16x8 __attribute__((ext_vector_type(8)));
typedef float f32x4 __attribute__((ext_vector_type(4)));

// Native cast: compiler emits v_cvt_pk_bf16_f32 for adjacent pairs (RNE).
__device__ __forceinline__ unsigned short f2bf(float f) {
    union { __bf16 h; unsigned short u; } v;
    v.h = (__bf16)f;
    return v.u;
}

__device__ __forceinline__ f32x4 mfma16(bf16x8 a, bf16x8 b, f32x4 c) {
    return __builtin_amdgcn_mfma_f32_16x16x32_bf16(a, b, c, 0, 0, 0);
}

#define LOAD_LDS16(g, l)                                                      \
    __builtin_amdgcn_global_load_lds(                                         \
        (const __attribute__((address_space(1))) void*)(g),                   \
        (__attribute__((address_space(3))) void*)(l), 16, 0, 0)

// ---------------- fused f32 -> bf16 convert for all 3 arrays ----------------
__global__ __launch_bounds__(256) void cvt_all(
    const float* __restrict__ a, long na,    // quads
    const float* __restrict__ b, long nb,    // quads
    const float* __restrict__ c, long nc,    // quads
    unsigned short* __restrict__ oa, unsigned short* __restrict__ ob,
    unsigned short* __restrict__ oc) {
    const long ntot = na + nb + nc;
    long i = (long)blockIdx.x * blockDim.x + threadIdx.x;
    const long stride = (long)gridDim.x * blockDim.x;
    for (; i < ntot; i += stride) {
        const float* src;
        unsigned short* dst;
        long q = i;
        if (q < na) { src = a; dst = oa; }
        else if (q < na + nb) { q -= na; src = b; dst = ob; }
        else { q -= na + nb; src = c; dst = oc; }
        float4 v = *(const float4*)(src + q * 4);
        ushort4 o;
        o.x = f2bf(v.x); o.y = f2bf(v.y); o.z = f2bf(v.z); o.w = f2bf(v.w);
        *(ushort4*)(dst + q * 4) = o;
    }
}

// ---------------- GEMM: C[m,n] = sum_k A[m,k]*Bw[n,k] + bias[n] ----------------
// m97 structure: 128x128 tile, BK=32, 4 waves, global_load_lds(16B), dbuf LDS.
// __launch_bounds__(256,3): pin 3 blocks/CU (R10-verified). Do not restructure
// (R8/R11 deep-pipeline rewrites both lost at K=1024).
// MODE 0 epilogue: q scaled by 0.125*log2e -> attn softmax in log2 domain.
template <int MODE>
__global__ __launch_bounds__(256, 3) void gemm_bt(
    const unsigned short* __restrict__ A,    // [M][K] bf16
    const unsigned short* __restrict__ Bw,   // [N][K] bf16
    const float* __restrict__ bias,          // [N]
    unsigned short* __restrict__ qb, unsigned short* __restrict__ kb,
    unsigned short* __restrict__ vtb, float* __restrict__ outf,
    int M, int N, int K) {
    __shared__ unsigned short As[2][128 * 32];
    __shared__ unsigned short Bs[2][128 * 32];
    const int tid = threadIdx.x;
    const int w = tid >> 6, lane = tid & 63;
    const int g = lane >> 4, q16 = lane & 15;
    const int wr = w >> 1, wc = w & 1;
    const int mbase = blockIdx.x * 128;
    const int nbase = blockIdx.y * 128;
    const int srow = lane >> 2;
    const int scol = (lane & 3) * 8;

    f32x4 acc[4][4];
#pragma unroll
    for (int i = 0; i < 4; ++i)
#pragma unroll
        for (int j = 0; j < 4; ++j) acc[i][j] = (f32x4){0.f, 0.f, 0.f, 0.f};

    const int nk = K >> 5;

    auto stage = [&](int buf, int t) {
        const int k0 = t << 5;
#pragma unroll
        for (int ii = 0; ii < 2; ++ii) {
            const int i = w + ii * 4;
            const unsigned short* ga =
                A + (long)(mbase + i * 16 + srow) * K + k0 + scol;
            LOAD_LDS16(ga, &As[buf][i * 512]);
            const unsigned short* gb =
                Bw + (long)(nbase + i * 16 + srow) * K + k0 + scol;
            LOAD_LDS16(gb, &Bs[buf][i * 512]);
        }
    };

    stage(0, 0);
    __syncthreads();
    int cur = 0;
    for (int t = 0; t < nk; ++t) {
        if (t + 1 < nk) stage(cur ^ 1, t + 1);
        bf16x8 af[4], bfr[4];
#pragma unroll
        for (int mi = 0; mi < 4; ++mi)
            af[mi] = *(const bf16x8*)&As[cur][(wr * 64 + mi * 16 + q16) * 32 + 8 * g];
#pragma unroll
        for (int ni = 0; ni < 4; ++ni)
            bfr[ni] = *(const bf16x8*)&Bs[cur][(wc * 64 + ni * 16 + q16) * 32 + 8 * g];
#pragma unroll
        for (int mi = 0; mi < 4; ++mi)
#pragma unroll
            for (int ni = 0; ni < 4; ++ni)
                acc[mi][ni] = mfma16(af[mi], bfr[ni], acc[mi][ni]);
        __syncthreads();
        cur ^= 1;
    }

#pragma unroll
    for (int mi = 0; mi < 4; ++mi) {
#pragma unroll
        for (int ni = 0; ni < 4; ++ni) {
            const int n = nbase + wc * 64 + ni * 16 + q16;
            const float bv = bias[n];
#pragma unroll
            for (int r = 0; r < 4; ++r) {
                const int m = mbase + wr * 64 + mi * 16 + 4 * g + r;
                const float val = acc[mi][ni][r] + bv;
                if (MODE == 0) {
                    const int which = n >> 10, rem = n & 1023;
                    const int h = rem >> 6, d = rem & 63;
                    const int b = m >> 11, t = m & 2047;
                    const long bh = (long)(b * HH + h);
                    if (which == 0)  // 0.125 * log2(e): log2-domain softmax
                        qb[(bh * TT + t) * DD + d] =
                            f2bf(val * 0.18033688011112042f);
                    else if (which == 1)
                        kb[(bh * TT + t) * DD + d] = f2bf(val);
                    else
                        vtb[(bh * DD + d) * TT + t] = f2bf(val);
                } else {
                    outf[(long)m * N + n] = val;
                }
            }
        }
    }
}

// ------ causal flash attention (R14 + shfl-free common path) ----------------
// grid: flat 2048 blocks, XCD-swizzled; LPT (bx = 31-(swz&31), longest first).
// Cross-lane reduction elimination:
//  (1) defer vote uses IN-LANE max only: __all(t_inlane - mrow <= THR) over
//      the wave == __all(t_row - mrow <= THR), since row max = max of its 4
//      lanes' in-lane maxes and mrow is row-uniform. The 2 max-shfls move
//      inside the rare rescale branch.
//  (2) lrow is a PER-LANE partial sum (fs rescale is row-uniform so partials
//      stay consistent); the 2 sum-shfls run ONCE after the loop, not per tile.
// Common-path tiles: ZERO shfl_xor (one wave vote only).
// Rest is R14-exact: swapped QK^T, log2-domain softmax, source-XOR-swizzled
// gload_lds staging (dbuf), plds stride-64 XOR, setprio, LDS 40960 B.
__global__ __launch_bounds__(256, 4) void attn_fwd(
    const unsigned short* __restrict__ qb, const unsigned short* __restrict__ kb,
    const unsigned short* __restrict__ vtb, unsigned short* __restrict__ attb) {
    __shared__ __align__(16) unsigned short Ks[2][64 * 64];
    __shared__ __align__(16) unsigned short Vs[2][64 * 64];
    __shared__ __align__(16) unsigned short plds[4][16 * 64];
    const int tid = threadIdx.x;
    const int w = tid >> 6, lane = tid & 63;
    const int g = lane >> 4, q16 = lane & 15;
    const int bid = blockIdx.x;
    const int swz = (bid & 7) * 256 + (bid >> 3);   // 2048 % 8 == 0: bijective
    const int bx = 31 - (swz & 31);                 // LPT: big bx first
    const int bh = swz >> 5;
    const int b = bh >> 4, h = bh & 15;
    const int qbase = bx * 64 + w * 16;

    const unsigned short* Q = qb + (long)bh * TT * DD;
    const unsigned short* Kp = kb + (long)bh * TT * DD;
    const unsigned short* Vt = vtb + (long)bh * DD * TT;

    const int srow = tid >> 3;                       // 0..31
    const int ssl = ((tid & 7) ^ (srow & 7)) * 8;    // swizzled col (shorts)
    unsigned short* kdst0 = &Ks[0][0] + w * 512;     // wave-uniform dests
    unsigned short* vdst0 = &Vs[0][0] + w * 512;

    auto stageKV = [&](int buf, int kt) {
        const long kb0 = (long)kt * 64;
        const unsigned short* gk = Kp + (kb0 + srow) * DD + ssl;
        const unsigned short* gv = Vt + (long)srow * TT + kb0 + ssl;
        unsigned short* kd = kdst0 + buf * 4096;
        unsigned short* vd = vdst0 + buf * 4096;
        LOAD_LDS16(gk, kd);
        LOAD_LDS16(gk + 32l * DD, kd + 2048);
        LOAD_LDS16(gv, vd);
        LOAD_LDS16(gv + 32l * TT, vd + 2048);
    };

    bf16x8 aq0 = *(const bf16x8*)&Q[(qbase + q16) * DD + 8 * g];
    bf16x8 aq1 = *(const bf16x8*)&Q[(qbase + q16) * DD + 32 + 8 * g];

    f32x4 acc[4];
#pragma unroll
    for (int i = 0; i < 4; ++i) acc[i] = (f32x4){0.f, 0.f, 0.f, 0.f};
    float mrow = -1e30f, lrow = 0.f;  // lrow: per-lane PARTIAL (16 k-slots)

    const int slot0 = (g ^ (q16 & 7)) << 3;
    const int nkt = bx + 1;
    stageKV(0, 0);
    __syncthreads();
    int cur = 0;
    for (int kt = 0; kt < nkt; ++kt) {
        if (kt + 1 < nkt) stageKV(cur ^ 1, kt + 1);
        const int kbase = kt * 64;
        f32x4 p[4];
#pragma unroll
        for (int s = 0; s < 4; ++s) p[s] = (f32x4){0.f, 0.f, 0.f, 0.f};
        __builtin_amdgcn_s_setprio(1);
#pragma unroll
        for (int s = 0; s < 4; ++s) {
            const int kr = (16 * s + q16) * 64;
            bf16x8 bk0 = *(const bf16x8*)&Ks[cur][kr + slot0];
            bf16x8 bk1 = *(const bf16x8*)&Ks[cur][kr + (slot0 ^ 32)];
            p[s] = mfma16(bk0, aq0, p[s]);
            p[s] = mfma16(bk1, aq1, p[s]);
        }
        __builtin_amdgcn_s_setprio(0);
        const int q = qbase + q16;
        if (kt == nkt - 1) {
#pragma unroll
            for (int s = 0; s < 4; ++s)
#pragma unroll
                for (int r = 0; r < 4; ++r)
                    if (kbase + 16 * s + 4 * g + r > q) p[s][r] = -1e30f;
        }
        // in-lane max only (no shfls) -- see note (1) above
        float t = fmaxf(fmaxf(p[0][0], p[0][1]), fmaxf(p[0][2], p[0][3]));
#pragma unroll
        for (int s = 1; s < 4; ++s)
            t = fmaxf(t, fmaxf(fmaxf(p[s][0], p[s][1]), fmaxf(p[s][2], p[s][3])));
        if (__all(t - mrow <= 11.541560327111708f)) {  // 8*log2e
            float ssum = 0.f;
#pragma unroll
            for (int s = 0; s < 4; ++s)
#pragma unroll
                for (int r = 0; r < 4; ++r) {
                    p[s][r] = __builtin_amdgcn_exp2f(p[s][r] - mrow);
                    ssum += p[s][r];
                }
            lrow += ssum;  // per-lane partial; cross-lane sum after loop
        } else {
            // full row max needed only here (rare)
            t = fmaxf(t, __shfl_xor(t, 16));
            t = fmaxf(t, __shfl_xor(t, 32));
            const float nm = fmaxf(mrow, t);
            const float fs = __builtin_amdgcn_exp2f(mrow - nm);
            mrow = nm;
            float ssum = 0.f;
#pragma unroll
            for (int s = 0; s < 4; ++s)
#pragma unroll
                for (int r = 0; r < 4; ++r) {
                    p[s][r] = __builtin_amdgcn_exp2f(p[s][r] - nm);
                    ssum += p[s][r];
                }
            lrow = lrow * fs + ssum;  // fs row-uniform -> partials consistent
            float fr[4];
#pragma unroll
            for (int r = 0; r < 4; ++r) fr[r] = __shfl(fs, 4 * g + r);
#pragma unroll
            for (int ni = 0; ni < 4; ++ni)
#pragma unroll
                for (int r = 0; r < 4; ++r) acc[ni][r] *= fr[r];
        }
#pragma unroll
        for (int s = 0; s < 4; ++s) {
            ushort4 pk;
            pk.x = f2bf(p[s][0]); pk.y = f2bf(p[s][1]);
            pk.z = f2bf(p[s][2]); pk.w = f2bf(p[s][3]);
            const int Gp = ((2 * s + (g >> 1)) ^ (q16 & 7)) * 8 + (g & 1) * 4;
            *(ushort4*)&plds[w][q16 * 64 + Gp] = pk;
        }
        bf16x8 pa0 = *(const bf16x8*)&plds[w][q16 * 64 + slot0];
        bf16x8 pa1 = *(const bf16x8*)&plds[w][q16 * 64 + (slot0 ^ 32)];
        __builtin_amdgcn_s_setprio(1);
#pragma unroll
        for (int ni = 0; ni < 4; ++ni) {
            const int vr = (ni * 16 + q16) * 64;
            bf16x8 bv0 = *(const bf16x8*)&Vs[cur][vr + slot0];
            bf16x8 bv1 = *(const bf16x8*)&Vs[cur][vr + (slot0 ^ 32)];
            acc[ni] = mfma16(pa0, bv0, acc[ni]);
            acc[ni] = mfma16(pa1, bv1, acc[ni]);
        }
        __builtin_amdgcn_s_setprio(0);
        __syncthreads();
        cur ^= 1;
    }
    // one cross-lane denominator reduction for the whole kernel
    lrow += __shfl_xor(lrow, 16);
    lrow += __shfl_xor(lrow, 32);
    float inv[4];
#pragma unroll
    for (int r = 0; r < 4; ++r) inv[r] = 1.0f / __shfl(lrow, 4 * g + r);
#pragma unroll
    for (int ni = 0; ni < 4; ++ni)
#pragma unroll
        for (int r = 0; r < 4; ++r) {
            const int q = qbase + 4 * g + r;
            const int d = ni * 16 + q16;
            attb[(((long)b * TT + q) * HH + h) * DD + d] =
                f2bf(acc[ni][r] * inv[r]);
        }
}

extern "C" void kernel_launch(void* const* d_in, const int* in_sizes, int n_in,
                              void* d_out, int out_size, void* d_ws, size_t ws_size,
                              hipStream_t stream) {
    const float* x = (const float*)d_in[0];
    const float* Wqkv = (const float*)d_in[1];
    const float* bqkv = (const float*)d_in[2];
    const float* Wproj = (const float*)d_in[3];
    const float* bproj = (const float*)d_in[4];
    float* out = (float*)d_out;

    char* ws = (char*)d_ws;
    unsigned short* xb = (unsigned short*)(ws);                  // 16 MB (reused as attb)
    unsigned short* wqkvb = (unsigned short*)(ws + (16l << 20)); // 6 MB
    unsigned short* wprojb = (unsigned short*)(ws + (22l << 20));// 2 MB
    unsigned short* qb = (unsigned short*)(ws + (24l << 20));    // 16 MB
    unsigned short* kb = (unsigned short*)(ws + (40l << 20));    // 16 MB
    unsigned short* vtb = (unsigned short*)(ws + (56l << 20));   // 16 MB
    unsigned short* attb = xb;  // x dead after QKV GEMM; reuse

    cvt_all<<<2048, 256, 0, stream>>>(
        x, (long)BB * TT * CC / 4, Wqkv, (long)3 * CC * CC / 4, Wproj,
        (long)CC * CC / 4, xb, wqkvb, wprojb);

    gemm_bt<0><<<dim3(64, 24), 256, 0, stream>>>(xb, wqkvb, bqkv, qb, kb, vtb,
                                                 nullptr, BB * TT, 3 * CC, CC);
    attn_fwd<<<2048, 256, 0, stream>>>(qb, kb, vtb, attb);
    gemm_bt<1><<<dim3(64, 8), 256, 0, stream>>>(attb, wprojb, bproj, nullptr,
                                                nullptr, nullptr, out, BB * TT,
                                                CC, CC);
}

// Round 16
// 183.433 us; speedup vs baseline: 1.1740x; 1.0954x over previous
//
#include <hip/hip_runtime.h>
#include <hip/hip_bf16.h>
#include <stdint.h>

// Problem constants
constexpr int BB = 4, TT = 2048, CC = 1024, HH = 16, DD = 64;

typedef __bf16 bf16_t;
typedef bf16_t bf16x8 __attribute__((ext_vector_type(8)));
typedef float f32x4 __attribute__((ext_vector_type(4)));

// Native cast: compiler emits v_cvt_pk_bf16_f32 for adjacent pairs (RNE).
__device__ __forceinline__ unsigned short f2bf(float f) {
    union { __bf16 h; unsigned short u; } v;
    v.h = (__bf16)f;
    return v.u;
}

__device__ __forceinline__ f32x4 mfma16(bf16x8 a, bf16x8 b, f32x4 c) {
    return __builtin_amdgcn_mfma_f32_16x16x32_bf16(a, b, c, 0, 0, 0);
}

#define LOAD_LDS16(g, l)                                                      \
    __builtin_amdgcn_global_load_lds(                                         \
        (const __attribute__((address_space(1))) void*)(g),                   \
        (__attribute__((address_space(3))) void*)(l), 16, 0, 0)

// ---------------- fused f32 -> bf16 convert for all 3 arrays ----------------
__global__ __launch_bounds__(256) void cvt_all(
    const float* __restrict__ a, long na,    // quads
    const float* __restrict__ b, long nb,    // quads
    const float* __restrict__ c, long nc,    // quads
    unsigned short* __restrict__ oa, unsigned short* __restrict__ ob,
    unsigned short* __restrict__ oc) {
    const long ntot = na + nb + nc;
    long i = (long)blockIdx.x * blockDim.x + threadIdx.x;
    const long stride = (long)gridDim.x * blockDim.x;
    for (; i < ntot; i += stride) {
        const float* src;
        unsigned short* dst;
        long q = i;
        if (q < na) { src = a; dst = oa; }
        else if (q < na + nb) { q -= na; src = b; dst = ob; }
        else { q -= na + nb; src = c; dst = oc; }
        float4 v = *(const float4*)(src + q * 4);
        ushort4 o;
        o.x = f2bf(v.x); o.y = f2bf(v.y); o.z = f2bf(v.z); o.w = f2bf(v.w);
        *(ushort4*)(dst + q * 4) = o;
    }
}

// ---------------- GEMM: C[m,n] = sum_k A[m,k]*Bw[n,k] + bias[n] ----------------
// m97 structure: 128x128 tile, BK=32, 4 waves, global_load_lds(16B), dbuf LDS.
// __launch_bounds__(256,3): pin 3 blocks/CU (R10-verified). Do not restructure
// the K-loop (R8/R11 deep-pipeline rewrites both lost at K=1024).
// MODE 0 epilogue: q scaled by 0.125*log2e (log2-domain softmax downstream).
//   which==2 (v) blocks: LDS-transpose epilogue — pack r-quads as ushort4 into
//   a [2][64][136] d-major tile (8-slot-chunk XOR c^=d&7 on both sides), then
//   coalesced 16B v^T stores. Replaces 64x 2B scatter at 4KB stride.
// MODE 1: f32 out[m*N+n] (coalesced, direct).
template <int MODE>
__global__ __launch_bounds__(256, 3) void gemm_bt(
    const unsigned short* __restrict__ A,    // [M][K] bf16
    const unsigned short* __restrict__ Bw,   // [N][K] bf16
    const float* __restrict__ bias,          // [N]
    unsigned short* __restrict__ qb, unsigned short* __restrict__ kb,
    unsigned short* __restrict__ vtb, float* __restrict__ outf,
    int M, int N, int K) {
    // As = smem[0..8191], Bs = smem[8192..16383] (2 bufs x 4096 shorts each);
    // v-epilogue reuses smem as OT[2][64][136] = 17408 shorts (34816 B).
    __shared__ __align__(16) unsigned short smem[17408];
    unsigned short* Asb = smem;
    unsigned short* Bsb = smem + 8192;
    const int tid = threadIdx.x;
    const int w = tid >> 6, lane = tid & 63;
    const int g = lane >> 4, q16 = lane & 15;
    const int wr = w >> 1, wc = w & 1;
    const int mbase = blockIdx.x * 128;
    const int nbase = blockIdx.y * 128;
    const int srow = lane >> 2;
    const int scol = (lane & 3) * 8;

    f32x4 acc[4][4];
#pragma unroll
    for (int i = 0; i < 4; ++i)
#pragma unroll
        for (int j = 0; j < 4; ++j) acc[i][j] = (f32x4){0.f, 0.f, 0.f, 0.f};

    const int nk = K >> 5;

    auto stage = [&](int buf, int t) {
        const int k0 = t << 5;
#pragma unroll
        for (int ii = 0; ii < 2; ++ii) {
            const int i = w + ii * 4;
            const unsigned short* ga =
                A + (long)(mbase + i * 16 + srow) * K + k0 + scol;
            LOAD_LDS16(ga, &Asb[buf * 4096 + i * 512]);
            const unsigned short* gb =
                Bw + (long)(nbase + i * 16 + srow) * K + k0 + scol;
            LOAD_LDS16(gb, &Bsb[buf * 4096 + i * 512]);
        }
    };

    stage(0, 0);
    __syncthreads();
    int cur = 0;
    for (int t = 0; t < nk; ++t) {
        if (t + 1 < nk) stage(cur ^ 1, t + 1);
        bf16x8 af[4], bfr[4];
#pragma unroll
        for (int mi = 0; mi < 4; ++mi)
            af[mi] = *(const bf16x8*)&Asb[cur * 4096 +
                                          (wr * 64 + mi * 16 + q16) * 32 + 8 * g];
#pragma unroll
        for (int ni = 0; ni < 4; ++ni)
            bfr[ni] = *(const bf16x8*)&Bsb[cur * 4096 +
                                           (wc * 64 + ni * 16 + q16) * 32 + 8 * g];
#pragma unroll
        for (int mi = 0; mi < 4; ++mi)
#pragma unroll
            for (int ni = 0; ni < 4; ++ni)
                acc[mi][ni] = mfma16(af[mi], bfr[ni], acc[mi][ni]);
        __syncthreads();
        cur ^= 1;
    }

    if (MODE == 0 && (nbase >> 10) == 2) {
        // ---- v-block: LDS transpose epilogue (As/Bs dead after final barrier)
        const int bb = mbase >> 11, t0 = mbase & 2047;
        const int h0 = (nbase & 1023) >> 6;
#pragma unroll
        for (int mi = 0; mi < 4; ++mi) {
#pragma unroll
            for (int ni = 0; ni < 4; ++ni) {
                const int nl = wc * 64 + ni * 16 + q16;   // 0..127
                const int hh = nl >> 6, d = nl & 63;
                const float bv = bias[nbase + nl];
                ushort4 pk;
                pk.x = f2bf(acc[mi][ni][0] + bv);
                pk.y = f2bf(acc[mi][ni][1] + bv);
                pk.z = f2bf(acc[mi][ni][2] + bv);
                pk.w = f2bf(acc[mi][ni][3] + bv);
                const int tb = wr * 64 + mi * 16 + 4 * g;  // t' of r=0
                const int cp = (tb >> 3) ^ (d & 7);        // chunk XOR swizzle
                const int pos = cp * 8 + (tb & 7);         // tb&7 = 4*(g&1)
                *(ushort4*)&smem[hh * 8704 + d * 136 + pos] = pk;
            }
        }
        __syncthreads();
        // copy-out: 2 h x 64 d x 16 chunks of 8 t = 2048 16B tasks, 8 iters
#pragma unroll
        for (int it = 0; it < 8; ++it) {
            const int task = it * 256 + tid;
            const int hh = task >> 10, d = (task >> 4) & 63, cr = task & 15;
            const int cp = cr ^ (d & 7);
            uint4 v4 = *(const uint4*)&smem[hh * 8704 + d * 136 + cp * 8];
            const long off =
                ((long)(bb * HH + h0 + hh) * DD + d) * TT + t0 + cr * 8;
            *(uint4*)&vtb[off] = v4;
        }
        return;
    }

#pragma unroll
    for (int mi = 0; mi < 4; ++mi) {
#pragma unroll
        for (int ni = 0; ni < 4; ++ni) {
            const int n = nbase + wc * 64 + ni * 16 + q16;
            const float bv = bias[n];
#pragma unroll
            for (int r = 0; r < 4; ++r) {
                const int m = mbase + wr * 64 + mi * 16 + 4 * g + r;
                const float val = acc[mi][ni][r] + bv;
                if (MODE == 0) {
                    const int which = n >> 10, rem = n & 1023;
                    const int h = rem >> 6, d = rem & 63;
                    const int b = m >> 11, t = m & 2047;
                    const long bh = (long)(b * HH + h);
                    if (which == 0)  // 0.125 * log2(e): log2-domain softmax
                        qb[(bh * TT + t) * DD + d] =
                            f2bf(val * 0.18033688011112042f);
                    else
                        kb[(bh * TT + t) * DD + d] = f2bf(val);
                } else {
                    outf[(long)m * N + n] = val;
                }
            }
        }
    }
}

// ------ causal flash attention (R15: shfl-free common path) -----------------
// grid: flat 2048 blocks, XCD-swizzled; LPT (bx = 31-(swz&31), longest first).
// Swapped QK^T, log2-domain softmax (Q pre-scaled by log2e), defer vote on
// in-lane max only, per-lane partial denominator (cross-lane sum once after
// the loop), source-XOR-swizzled gload_lds staging (dbuf), plds stride-64
// XOR, setprio on MFMA clusters, LDS 40960 B = 4 blocks/CU.
__global__ __launch_bounds__(256, 4) void attn_fwd(
    const unsigned short* __restrict__ qb, const unsigned short* __restrict__ kb,
    const unsigned short* __restrict__ vtb, unsigned short* __restrict__ attb) {
    __shared__ __align__(16) unsigned short Ks[2][64 * 64];
    __shared__ __align__(16) unsigned short Vs[2][64 * 64];
    __shared__ __align__(16) unsigned short plds[4][16 * 64];
    const int tid = threadIdx.x;
    const int w = tid >> 6, lane = tid & 63;
    const int g = lane >> 4, q16 = lane & 15;
    const int bid = blockIdx.x;
    const int swz = (bid & 7) * 256 + (bid >> 3);   // 2048 % 8 == 0: bijective
    const int bx = 31 - (swz & 31);                 // LPT: big bx first
    const int bh = swz >> 5;
    const int b = bh >> 4, h = bh & 15;
    const int qbase = bx * 64 + w * 16;

    const unsigned short* Q = qb + (long)bh * TT * DD;
    const unsigned short* Kp = kb + (long)bh * TT * DD;
    const unsigned short* Vt = vtb + (long)bh * DD * TT;

    const int srow = tid >> 3;                       // 0..31
    const int ssl = ((tid & 7) ^ (srow & 7)) * 8;    // swizzled col (shorts)
    unsigned short* kdst0 = &Ks[0][0] + w * 512;     // wave-uniform dests
    unsigned short* vdst0 = &Vs[0][0] + w * 512;

    auto stageKV = [&](int buf, int kt) {
        const long kb0 = (long)kt * 64;
        const unsigned short* gk = Kp + (kb0 + srow) * DD + ssl;
        const unsigned short* gv = Vt + (long)srow * TT + kb0 + ssl;
        unsigned short* kd = kdst0 + buf * 4096;
        unsigned short* vd = vdst0 + buf * 4096;
        LOAD_LDS16(gk, kd);
        LOAD_LDS16(gk + 32l * DD, kd + 2048);
        LOAD_LDS16(gv, vd);
        LOAD_LDS16(gv + 32l * TT, vd + 2048);
    };

    bf16x8 aq0 = *(const bf16x8*)&Q[(qbase + q16) * DD + 8 * g];
    bf16x8 aq1 = *(const bf16x8*)&Q[(qbase + q16) * DD + 32 + 8 * g];

    f32x4 acc[4];
#pragma unroll
    for (int i = 0; i < 4; ++i) acc[i] = (f32x4){0.f, 0.f, 0.f, 0.f};
    float mrow = -1e30f, lrow = 0.f;  // lrow: per-lane PARTIAL (16 k-slots)

    const int slot0 = (g ^ (q16 & 7)) << 3;
    const int nkt = bx + 1;
    stageKV(0, 0);
    __syncthreads();
    int cur = 0;
    for (int kt = 0; kt < nkt; ++kt) {
        if (kt + 1 < nkt) stageKV(cur ^ 1, kt + 1);
        const int kbase = kt * 64;
        f32x4 p[4];
#pragma unroll
        for (int s = 0; s < 4; ++s) p[s] = (f32x4){0.f, 0.f, 0.f, 0.f};
        __builtin_amdgcn_s_setprio(1);
#pragma unroll
        for (int s = 0; s < 4; ++s) {
            const int kr = (16 * s + q16) * 64;
            bf16x8 bk0 = *(const bf16x8*)&Ks[cur][kr + slot0];
            bf16x8 bk1 = *(const bf16x8*)&Ks[cur][kr + (slot0 ^ 32)];
            p[s] = mfma16(bk0, aq0, p[s]);
            p[s] = mfma16(bk1, aq1, p[s]);
        }
        __builtin_amdgcn_s_setprio(0);
        const int q = qbase + q16;
        if (kt == nkt - 1) {
#pragma unroll
            for (int s = 0; s < 4; ++s)
#pragma unroll
                for (int r = 0; r < 4; ++r)
                    if (kbase + 16 * s + 4 * g + r > q) p[s][r] = -1e30f;
        }
        // in-lane max only (no shfls)
        float t = fmaxf(fmaxf(p[0][0], p[0][1]), fmaxf(p[0][2], p[0][3]));
#pragma unroll
        for (int s = 1; s < 4; ++s)
            t = fmaxf(t, fmaxf(fmaxf(p[s][0], p[s][1]), fmaxf(p[s][2], p[s][3])));
        if (__all(t - mrow <= 11.541560327111708f)) {  // 8*log2e
            float ssum = 0.f;
#pragma unroll
            for (int s = 0; s < 4; ++s)
#pragma unroll
                for (int r = 0; r < 4; ++r) {
                    p[s][r] = __builtin_amdgcn_exp2f(p[s][r] - mrow);
                    ssum += p[s][r];
                }
            lrow += ssum;  // per-lane partial
        } else {
            t = fmaxf(t, __shfl_xor(t, 16));
            t = fmaxf(t, __shfl_xor(t, 32));
            const float nm = fmaxf(mrow, t);
            const float fs = __builtin_amdgcn_exp2f(mrow - nm);
            mrow = nm;
            float ssum = 0.f;
#pragma unroll
            for (int s = 0; s < 4; ++s)
#pragma unroll
                for (int r = 0; r < 4; ++r) {
                    p[s][r] = __builtin_amdgcn_exp2f(p[s][r] - nm);
                    ssum += p[s][r];
                }
            lrow = lrow * fs + ssum;  // fs row-uniform -> partials consistent
            float fr[4];
#pragma unroll
            for (int r = 0; r < 4; ++r) fr[r] = __shfl(fs, 4 * g + r);
#pragma unroll
            for (int ni = 0; ni < 4; ++ni)
#pragma unroll
                for (int r = 0; r < 4; ++r) acc[ni][r] *= fr[r];
        }
#pragma unroll
        for (int s = 0; s < 4; ++s) {
            ushort4 pk;
            pk.x = f2bf(p[s][0]); pk.y = f2bf(p[s][1]);
            pk.z = f2bf(p[s][2]); pk.w = f2bf(p[s][3]);
            const int Gp = ((2 * s + (g >> 1)) ^ (q16 & 7)) * 8 + (g & 1) * 4;
            *(ushort4*)&plds[w][q16 * 64 + Gp] = pk;
        }
        bf16x8 pa0 = *(const bf16x8*)&plds[w][q16 * 64 + slot0];
        bf16x8 pa1 = *(const bf16x8*)&plds[w][q16 * 64 + (slot0 ^ 32)];
        __builtin_amdgcn_s_setprio(1);
#pragma unroll
        for (int ni = 0; ni < 4; ++ni) {
            const int vr = (ni * 16 + q16) * 64;
            bf16x8 bv0 = *(const bf16x8*)&Vs[cur][vr + slot0];
            bf16x8 bv1 = *(const bf16x8*)&Vs[cur][vr + (slot0 ^ 32)];
            acc[ni] = mfma16(pa0, bv0, acc[ni]);
            acc[ni] = mfma16(pa1, bv1, acc[ni]);
        }
        __builtin_amdgcn_s_setprio(0);
        __syncthreads();
        cur ^= 1;
    }
    // one cross-lane denominator reduction for the whole kernel
    lrow += __shfl_xor(lrow, 16);
    lrow += __shfl_xor(lrow, 32);
    float inv[4];
#pragma unroll
    for (int r = 0; r < 4; ++r) inv[r] = 1.0f / __shfl(lrow, 4 * g + r);
#pragma unroll
    for (int ni = 0; ni < 4; ++ni)
#pragma unroll
        for (int r = 0; r < 4; ++r) {
            const int q = qbase + 4 * g + r;
            const int d = ni * 16 + q16;
            attb[(((long)b * TT + q) * HH + h) * DD + d] =
                f2bf(acc[ni][r] * inv[r]);
        }
}

extern "C" void kernel_launch(void* const* d_in, const int* in_sizes, int n_in,
                              void* d_out, int out_size, void* d_ws, size_t ws_size,
                              hipStream_t stream) {
    const float* x = (const float*)d_in[0];
    const float* Wqkv = (const float*)d_in[1];
    const float* bqkv = (const float*)d_in[2];
    const float* Wproj = (const float*)d_in[3];
    const float* bproj = (const float*)d_in[4];
    float* out = (float*)d_out;

    char* ws = (char*)d_ws;
    unsigned short* xb = (unsigned short*)(ws);                  // 16 MB (reused as attb)
    unsigned short* wqkvb = (unsigned short*)(ws + (16l << 20)); // 6 MB
    unsigned short* wprojb = (unsigned short*)(ws + (22l << 20));// 2 MB
    unsigned short* qb = (unsigned short*)(ws + (24l << 20));    // 16 MB
    unsigned short* kb = (unsigned short*)(ws + (40l << 20));    // 16 MB
    unsigned short* vtb = (unsigned short*)(ws + (56l << 20));   // 16 MB
    unsigned short* attb = xb;  // x dead after QKV GEMM; reuse

    cvt_all<<<2048, 256, 0, stream>>>(
        x, (long)BB * TT * CC / 4, Wqkv, (long)3 * CC * CC / 4, Wproj,
        (long)CC * CC / 4, xb, wqkvb, wprojb);

    gemm_bt<0><<<dim3(64, 24), 256, 0, stream>>>(xb, wqkvb, bqkv, qb, kb, vtb,
                                                 nullptr, BB * TT, 3 * CC, CC);
    attn_fwd<<<2048, 256, 0, stream>>>(qb, kb, vtb, attb);
    gemm_bt<1><<<dim3(64, 8), 256, 0, stream>>>(attb, wprojb, bproj, nullptr,
                                                nullptr, nullptr, out, BB * TT,
                                                CC, CC);
}